// Round 5
// baseline (326.451 us; speedup 1.0000x reference)
//
#include <hip/hip_runtime.h>
#include <hip/hip_bf16.h>

typedef __attribute__((ext_vector_type(8))) short short8;
typedef __attribute__((ext_vector_type(4))) float floatx4;
typedef unsigned short u16;
typedef unsigned int u32;

#define QSCALE 0.1803368801111244f   // 0.125 * log2(e): folded into Q so softmax is exp2(S)

__device__ __forceinline__ u16 f2b(float f) {
    union { float f; u32 u; } v; v.f = f;
    u32 r = v.u + 0x7fffu + ((v.u >> 16) & 1u);   // RNE
    return (u16)(r >> 16);
}

__device__ __forceinline__ float b2f(u16 b) {
    u32 u = ((u32)b) << 16;
    union { u32 u; float f; } v; v.u = u;
    return v.f;
}

__device__ __forceinline__ u32 pk2(float a, float b) {
    __hip_bfloat162 w = __float22bfloat162_rn(make_float2(a, b));
    return *(u32*)&w;
}

__device__ __forceinline__ void gload(const u16* g, u16* l) {
    __builtin_amdgcn_global_load_lds((const __attribute__((address_space(1))) void*)g,
                                     (__attribute__((address_space(3))) void*)l, 16, 0, 0);
}

// ---------------- batched weight transpose + fp32->bf16 (16 x 512x512 tiles) ----------------
struct TPent { const float* s; u16* d; int O; int dI; };
struct TP16 { TPent e[16]; };
__global__ __launch_bounds__(256) void transpose_convert16(TP16 p) {
    __shared__ float t[32][33];
    TPent e = p.e[blockIdx.z];
    int o0 = blockIdx.x * 32, i0 = blockIdx.y * 32;
    int tx = threadIdx.x, ty = threadIdx.y;
#pragma unroll
    for (int k = 0; k < 32; k += 8) t[ty + k][tx] = e.s[(size_t)(i0 + ty + k) * e.O + o0 + tx];
    __syncthreads();
#pragma unroll
    for (int k = 0; k < 32; k += 8) e.d[(size_t)(o0 + ty + k) * e.dI + i0 + tx] = f2b(t[tx][ty + k]);
}

// gather 5 bias vectors into 2 concat buffers. grid 10 x 256
__global__ __launch_bounds__(256) void gather_bias(const float* b0, const float* b1, const float* b2,
                                                   const float* b3, const float* b4,
                                                   float* dqkv, float* dkv) {
    int i = blockIdx.x * 256 + threadIdx.x;
    if      (i < 512)  dqkv[i] = b0[i];
    else if (i < 1024) dqkv[i] = b1[i - 512];
    else if (i < 1536) dqkv[i] = b2[i - 1024];
    else if (i < 2048) dkv[i - 1536] = b3[i - 1536];
    else               dkv[i - 1536] = b4[i - 2048];
}

// fp32 -> bf16 for x and enc in one launch. grid 2048 x 256, 4 elems each.
__global__ __launch_bounds__(256) void cvt_bf16_2(const float4* __restrict__ s0, ushort4* __restrict__ d0,
                                                  const float4* __restrict__ s1, ushort4* __restrict__ d1) {
    int i = blockIdx.x * 256 + threadIdx.x;
    float4 v = s0[i];
    ushort4 o; o.x = f2b(v.x); o.y = f2b(v.y); o.z = f2b(v.z); o.w = f2b(v.w);
    d0[i] = o;
    v = s1[i];
    o.x = f2b(v.x); o.y = f2b(v.y); o.z = f2b(v.z); o.w = f2b(v.w);
    d1[i] = o;
}

// ============ GEMM family: BK=64, 128-byte LDS rows, both-sides XOR swizzle ============
// swizzle: stage column skseg = ((tid&7)*8) ^ ((srow&7)<<3); read col ko = (g4*8+kk*32) ^ ((c16&7)<<3).

// ---------------- GEMM 128x128 (m97 shape): 4 waves x 64x64 quadrant, 32 MFMA : 16 ds_read --
__global__ __launch_bounds__(256) void gemm128(
    const u16* __restrict__ A, int lda,
    const u16* __restrict__ B, int ldb,
    int K,
    const float* __restrict__ bias,
    u16* __restrict__ out_b,
    int out_stride, int scale_ncols, int gelu_flag)
{
    __shared__ u16 lA[128 * 64];
    __shared__ u16 lB[128 * 64];
    int tid = threadIdx.x, wave = tid >> 6, lane = tid & 63;
    int g4 = lane >> 4, c16 = lane & 15;
    int swz = (c16 & 7) << 3;
    int bm = blockIdx.x * 128, bn = blockIdx.y * 128;
    int wm = (wave >> 1) * 64, wn = (wave & 1) * 64;
    int srow = tid >> 3, skseg = ((tid & 7) * 8) ^ ((srow & 7) << 3);
    const u16* Ar = A + (size_t)(bm + srow) * lda + skseg;
    const u16* Br = B + (size_t)(bn + srow) * ldb + skseg;
    size_t a32 = (size_t)32 * lda, b32 = (size_t)32 * ldb;

    floatx4 acc[4][4];
#pragma unroll
    for (int i = 0; i < 4; i++)
#pragma unroll
        for (int j = 0; j < 4; j++) acc[i][j] = (floatx4){0.f, 0.f, 0.f, 0.f};

    for (int kt = 0; kt < K; kt += 64) {
        __syncthreads();
        gload(Ar + kt,           lA + wave * 512);
        gload(Ar + kt + a32,     lA + 2048 + wave * 512);
        gload(Ar + kt + 2 * a32, lA + 4096 + wave * 512);
        gload(Ar + kt + 3 * a32, lA + 6144 + wave * 512);
        gload(Br + kt,           lB + wave * 512);
        gload(Br + kt + b32,     lB + 2048 + wave * 512);
        gload(Br + kt + 2 * b32, lB + 4096 + wave * 512);
        gload(Br + kt + 3 * b32, lB + 6144 + wave * 512);
        __syncthreads();
#pragma unroll
        for (int kk = 0; kk < 2; kk++) {
            int ko = (g4 * 8 + kk * 32) ^ swz;
            short8 aF[4], bF[4];
#pragma unroll
            for (int i = 0; i < 4; i++) aF[i] = *(const short8*)&lA[(wm + i * 16 + c16) * 64 + ko];
#pragma unroll
            for (int j = 0; j < 4; j++) bF[j] = *(const short8*)&lB[(wn + j * 16 + c16) * 64 + ko];
#pragma unroll
            for (int i = 0; i < 4; i++)
#pragma unroll
                for (int j = 0; j < 4; j++)
                    acc[i][j] = __builtin_amdgcn_mfma_f32_16x16x32_bf16(aF[i], bF[j], acc[i][j], 0, 0, 0);
        }
    }

#pragma unroll
    for (int i = 0; i < 4; i++) {
        int row0 = bm + wm + i * 16 + g4 * 4;
#pragma unroll
        for (int j = 0; j < 4; j++) {
            int col = bn + wn + j * 16 + c16;
            float bv = bias[col];
#pragma unroll
            for (int r = 0; r < 4; r++) {
                float v = acc[i][j][r] + bv;
                if (col < scale_ncols) v *= QSCALE;
                if (gelu_flag) v = 0.5f * v * (1.f + erff(v * 0.70710678118654752f));
                out_b[(size_t)(row0 + r) * out_stride + col] = f2b(v);
            }
        }
    }
}

// ---------------- dual GEMM 128x128 (QKV_m for by<ys, KV_c for by>=ys), bf16 out -----------
__global__ __launch_bounds__(256) void gemm128_dual(
    const u16* __restrict__ A0, const u16* __restrict__ B0, const float* __restrict__ bias0,
    u16* __restrict__ out0, int ostride0, int scale0,
    const u16* __restrict__ A1, const u16* __restrict__ B1, const float* __restrict__ bias1,
    u16* __restrict__ out1, int ostride1,
    int ys, int K, int lda, int ldb)
{
    __shared__ u16 lA[128 * 64];
    __shared__ u16 lB[128 * 64];
    int tid = threadIdx.x, wave = tid >> 6, lane = tid & 63;
    int g4 = lane >> 4, c16 = lane & 15;
    int swz = (c16 & 7) << 3;
    int by = blockIdx.y;
    const u16* A; const u16* B; const float* bias; u16* out; int ostride, scaleN, bn;
    if (by < ys) { A = A0; B = B0; bias = bias0; out = out0; ostride = ostride0; scaleN = scale0; bn = by * 128; }
    else         { A = A1; B = B1; bias = bias1; out = out1; ostride = ostride1; scaleN = 0;      bn = (by - ys) * 128; }
    int bm = blockIdx.x * 128;
    int wm = (wave >> 1) * 64, wn = (wave & 1) * 64;
    int srow = tid >> 3, skseg = ((tid & 7) * 8) ^ ((srow & 7) << 3);
    const u16* Ar = A + (size_t)(bm + srow) * lda + skseg;
    const u16* Br = B + (size_t)(bn + srow) * ldb + skseg;
    size_t a32 = (size_t)32 * lda, b32 = (size_t)32 * ldb;

    floatx4 acc[4][4];
#pragma unroll
    for (int i = 0; i < 4; i++)
#pragma unroll
        for (int j = 0; j < 4; j++) acc[i][j] = (floatx4){0.f, 0.f, 0.f, 0.f};

    for (int kt = 0; kt < K; kt += 64) {
        __syncthreads();
        gload(Ar + kt,           lA + wave * 512);
        gload(Ar + kt + a32,     lA + 2048 + wave * 512);
        gload(Ar + kt + 2 * a32, lA + 4096 + wave * 512);
        gload(Ar + kt + 3 * a32, lA + 6144 + wave * 512);
        gload(Br + kt,           lB + wave * 512);
        gload(Br + kt + b32,     lB + 2048 + wave * 512);
        gload(Br + kt + 2 * b32, lB + 4096 + wave * 512);
        gload(Br + kt + 3 * b32, lB + 6144 + wave * 512);
        __syncthreads();
#pragma unroll
        for (int kk = 0; kk < 2; kk++) {
            int ko = (g4 * 8 + kk * 32) ^ swz;
            short8 aF[4], bF[4];
#pragma unroll
            for (int i = 0; i < 4; i++) aF[i] = *(const short8*)&lA[(wm + i * 16 + c16) * 64 + ko];
#pragma unroll
            for (int j = 0; j < 4; j++) bF[j] = *(const short8*)&lB[(wn + j * 16 + c16) * 64 + ko];
#pragma unroll
            for (int i = 0; i < 4; i++)
#pragma unroll
                for (int j = 0; j < 4; j++)
                    acc[i][j] = __builtin_amdgcn_mfma_f32_16x16x32_bf16(aF[i], bF[j], acc[i][j], 0, 0, 0);
        }
    }

#pragma unroll
    for (int i = 0; i < 4; i++) {
        int row0 = bm + wm + i * 16 + g4 * 4;
#pragma unroll
        for (int j = 0; j < 4; j++) {
            int col = bn + wn + j * 16 + c16;
            float bv = bias[col];
#pragma unroll
            for (int r = 0; r < 4; r++) {
                float v = acc[i][j][r] + bv;
                if (col < scaleN) v *= QSCALE;
                out[(size_t)(row0 + r) * ostride + col] = f2b(v);
            }
        }
    }
}

// ---------------- GEMM 64x128: full-K, epilogue with optional gelu/residual/fp32 out -------
__global__ __launch_bounds__(256) void gemm64x128(
    const u16* __restrict__ A, int lda,
    const u16* __restrict__ B, int ldb,
    int K,
    const float* __restrict__ bias,
    const float* __restrict__ residual,
    float* __restrict__ out_f, u16* __restrict__ out_b,
    int out_stride, int scale_ncols, int gelu_flag)
{
    __shared__ u16 lA[64 * 64];
    __shared__ u16 lB[128 * 64];
    int tid = threadIdx.x, wave = tid >> 6, lane = tid & 63;
    int g4 = lane >> 4, c16 = lane & 15;
    int swz = (c16 & 7) << 3;
    int bm = blockIdx.x * 64, bn = blockIdx.y * 128;
    int wm = (wave >> 1) * 32, wn = (wave & 1) * 64;
    int srow = tid >> 3, skseg = ((tid & 7) * 8) ^ ((srow & 7) << 3);
    const u16* Ar = A + (size_t)(bm + srow) * lda + skseg;
    const u16* Br = B + (size_t)(bn + srow) * ldb + skseg;
    size_t a32 = (size_t)32 * lda, b32 = (size_t)32 * ldb;

    floatx4 acc[2][4];
#pragma unroll
    for (int i = 0; i < 2; i++)
#pragma unroll
        for (int j = 0; j < 4; j++) acc[i][j] = (floatx4){0.f, 0.f, 0.f, 0.f};

    for (int kt = 0; kt < K; kt += 64) {
        __syncthreads();
        gload(Ar + kt,           lA + wave * 512);
        gload(Ar + kt + a32,     lA + 2048 + wave * 512);
        gload(Br + kt,           lB + wave * 512);
        gload(Br + kt + b32,     lB + 2048 + wave * 512);
        gload(Br + kt + 2 * b32, lB + 4096 + wave * 512);
        gload(Br + kt + 3 * b32, lB + 6144 + wave * 512);
        __syncthreads();
        short8 aF[2][2], bF[2][4];
#pragma unroll
        for (int kk = 0; kk < 2; kk++) {
            int ko = (g4 * 8 + kk * 32) ^ swz;
#pragma unroll
            for (int i = 0; i < 2; i++) aF[kk][i] = *(const short8*)&lA[(wm + i * 16 + c16) * 64 + ko];
#pragma unroll
            for (int j = 0; j < 4; j++) bF[kk][j] = *(const short8*)&lB[(wn + j * 16 + c16) * 64 + ko];
        }
#pragma unroll
        for (int kk = 0; kk < 2; kk++)
#pragma unroll
            for (int i = 0; i < 2; i++)
#pragma unroll
                for (int j = 0; j < 4; j++)
                    acc[i][j] = __builtin_amdgcn_mfma_f32_16x16x32_bf16(aF[kk][i], bF[kk][j], acc[i][j], 0, 0, 0);
    }

#pragma unroll
    for (int i = 0; i < 2; i++) {
        int row0 = bm + wm + i * 16 + g4 * 4;
#pragma unroll
        for (int j = 0; j < 4; j++) {
            int col = bn + wn + j * 16 + c16;
            float bv = bias[col];
#pragma unroll
            for (int r = 0; r < 4; r++) {
                int row = row0 + r;
                float v = acc[i][j][r] + bv;
                if (col < scale_ncols) v *= QSCALE;
                if (gelu_flag) v = 0.5f * v * (1.f + erff(v * 0.70710678118654752f));
                if (residual) v += residual[(size_t)row * out_stride + col];
                if (out_f) out_f[(size_t)row * out_stride + col] = v;
                else       out_b[(size_t)row * out_stride + col] = f2b(v);
            }
        }
    }
}

// ---------------- GEMM 64x128 K-split-2: bf16 partials. grid (M/64, N/128, 2) --------------
// sp==0 adds bias + residual (fp32 OR bf16 source). Consumer (LN) adds the two bf16 slabs.
__global__ __launch_bounds__(256) void gemm64x128s(
    const u16* __restrict__ A, int lda,
    const u16* __restrict__ B, int ldb,
    int Ksub,
    const float* __restrict__ bias,
    const float* __restrict__ res_f,
    const u16* __restrict__ res_b,
    u16* __restrict__ out0, int out_stride)
{
    __shared__ u16 lA[64 * 64];
    __shared__ u16 lB[128 * 64];
    int tid = threadIdx.x, wave = tid >> 6, lane = tid & 63;
    int g4 = lane >> 4, c16 = lane & 15;
    int swz = (c16 & 7) << 3;
    int bm = blockIdx.x * 64, bn = blockIdx.y * 128, sp = blockIdx.z;
    int wm = (wave >> 1) * 32, wn = (wave & 1) * 64;
    int srow = tid >> 3;
    int skseg = (((tid & 7) * 8) ^ ((srow & 7) << 3)) + sp * Ksub;
    const u16* Ar = A + (size_t)(bm + srow) * lda + skseg;
    const u16* Br = B + (size_t)(bn + srow) * ldb + skseg;
    size_t a32 = (size_t)32 * lda, b32 = (size_t)32 * ldb;

    floatx4 acc[2][4];
#pragma unroll
    for (int i = 0; i < 2; i++)
#pragma unroll
        for (int j = 0; j < 4; j++) acc[i][j] = (floatx4){0.f, 0.f, 0.f, 0.f};

    for (int kt = 0; kt < Ksub; kt += 64) {
        __syncthreads();
        gload(Ar + kt,           lA + wave * 512);
        gload(Ar + kt + a32,     lA + 2048 + wave * 512);
        gload(Br + kt,           lB + wave * 512);
        gload(Br + kt + b32,     lB + 2048 + wave * 512);
        gload(Br + kt + 2 * b32, lB + 4096 + wave * 512);
        gload(Br + kt + 3 * b32, lB + 6144 + wave * 512);
        __syncthreads();
        short8 aF[2][2], bF[2][4];
#pragma unroll
        for (int kk = 0; kk < 2; kk++) {
            int ko = (g4 * 8 + kk * 32) ^ swz;
#pragma unroll
            for (int i = 0; i < 2; i++) aF[kk][i] = *(const short8*)&lA[(wm + i * 16 + c16) * 64 + ko];
#pragma unroll
            for (int j = 0; j < 4; j++) bF[kk][j] = *(const short8*)&lB[(wn + j * 16 + c16) * 64 + ko];
        }
#pragma unroll
        for (int kk = 0; kk < 2; kk++)
#pragma unroll
            for (int i = 0; i < 2; i++)
#pragma unroll
                for (int j = 0; j < 4; j++)
                    acc[i][j] = __builtin_amdgcn_mfma_f32_16x16x32_bf16(aF[kk][i], bF[kk][j], acc[i][j], 0, 0, 0);
    }

    u16* out = out0 + (size_t)sp * 4096 * 512;
#pragma unroll
    for (int i = 0; i < 2; i++) {
        int row0 = bm + wm + i * 16 + g4 * 4;
#pragma unroll
        for (int j = 0; j < 4; j++) {
            int col = bn + wn + j * 16 + c16;
            float bv = (sp == 0) ? bias[col] : 0.f;
#pragma unroll
            for (int r = 0; r < 4; r++) {
                int row = row0 + r;
                float v = acc[i][j][r] + bv;
                if (sp == 0) {
                    if (res_f)      v += res_f[(size_t)row * out_stride + col];
                    else if (res_b) v += b2f(res_b[(size_t)row * out_stride + col]);
                }
                out[(size_t)row * out_stride + col] = f2b(v);
            }
        }
    }
}

// ============ attention common: 32 q-rows per wave (2 q-subtiles), K/V frags read once ======
// K rows staged in permuted order row(k) = 16*(2*(k>>5)+((k>>2)&1)) + 4*((k>>3)&3) + (k&3):
// S^T lands so PV A-frags are a pure register repack. V transposed+swizzled in LDS.

// ---------------- cross attention: 128-row Q blocks, 4-way key split. grid 1024 -------------
__global__ __launch_bounds__(256, 3) void attn_cross(
    const u16* __restrict__ Qp, int q_stride,
    const u16* __restrict__ Kp, int kv_stride,
    const u16* __restrict__ Vp,
    u16* __restrict__ Opart,     // [4][16][2048][64] bf16
    float* __restrict__ Lpart)   // [4][16][2048]
{
    __shared__ u16 lK[64 * 72];
    __shared__ u16 lVT[64 * 72];
    int tid = threadIdx.x, wave = tid >> 6, lane = tid & 63;
    int g4 = lane >> 4, c16 = lane & 15;
    int id = blockIdx.x;
    int bh = (id & 7) | ((id >> 3 & 1) << 3);
    int rest = id >> 4;            // 0..63
    int qt = rest & 15;            // 128-row q tile
    int sp = rest >> 4;            // 0..3
    size_t rowbase = (size_t)(bh >> 3) * 2048;
    int hoff = (bh & 7) * 64;
    const u16* Q = Qp + rowbase * q_stride + hoff;
    const u16* K = Kp + rowbase * kv_stride + hoff;
    const u16* V = Vp + rowbase * kv_stride + hoff;

    int qbase = qt * 128 + wave * 32;
    short8 qf[2][2];
#pragma unroll
    for (int qc = 0; qc < 2; qc++) {
        qf[qc][0] = *(const short8*)&Q[(size_t)(qbase + qc * 16 + c16) * q_stride + g4 * 8];
        qf[qc][1] = *(const short8*)&Q[(size_t)(qbase + qc * 16 + c16) * q_stride + g4 * 8 + 32];
    }

    int kr = tid >> 2, ks = (tid & 3) * 16;
    int krow = 16 * (2 * (kr >> 5) + ((kr >> 2) & 1)) + 4 * ((kr >> 3) & 3) + (kr & 3);
    const u16* Kbase = K + (size_t)kr * kv_stride + ks;
    int vk0 = (tid >> 3) * 2, vs = (tid & 7) * 8;
    const u16* Vbase = V + (size_t)vk0 * kv_stride + vs;

    int4 kv0, kv1, vv0, vv1;
    auto load_tile = [&](int kt) {
        const u16* kp = Kbase + (size_t)kt * 64 * kv_stride;
        kv0 = *(const int4*)(kp);
        kv1 = *(const int4*)(kp + 8);
        const u16* vp = Vbase + (size_t)kt * 64 * kv_stride;
        vv0 = *(const int4*)(vp);
        vv1 = *(const int4*)(vp + kv_stride);
    };
    auto store_tile = [&]() {
        *(int4*)&lK[krow * 72 + ks] = kv0;
        *(int4*)&lK[krow * 72 + ks + 8] = kv1;
        const u16* pa = (const u16*)&vv0;
        const u16* pb = (const u16*)&vv1;
#pragma unroll
        for (int j = 0; j < 8; j++) {
            int dh = vs + j;
            int keyS = vk0 ^ (((dh >> 3) & 3) << 4);
            u32 w = (u32)pa[j] | ((u32)pb[j] << 16);
            *(u32*)&lVT[dh * 72 + keyS] = w;
        }
    };

    floatx4 o[2][4];
#pragma unroll
    for (int qc = 0; qc < 2; qc++)
#pragma unroll
        for (int d = 0; d < 4; d++) o[qc][d] = (floatx4){0.f, 0.f, 0.f, 0.f};
    float ls0 = 0.f, ls1 = 0.f;

    int kt = sp;
    load_tile(kt);
    for (; kt < 32; kt += 4) {
        __syncthreads();
        store_tile();
        __syncthreads();
        if (kt + 4 < 32) load_tile(kt + 4);

        short8 b0[4], b1[4];
#pragma unroll
        for (int nt = 0; nt < 4; nt++) {
            b0[nt] = *(const short8*)&lK[(nt * 16 + c16) * 72 + g4 * 8];
            b1[nt] = *(const short8*)&lK[(nt * 16 + c16) * 72 + g4 * 8 + 32];
        }
        short8 pa[2][2];
#pragma unroll
        for (int qc = 0; qc < 2; qc++) {
            floatx4 sc[4];
#pragma unroll
            for (int nt = 0; nt < 4; nt++) {
                floatx4 z = (floatx4){0.f, 0.f, 0.f, 0.f};
                z = __builtin_amdgcn_mfma_f32_16x16x32_bf16(b0[nt], qf[qc][0], z, 0, 0, 0);
                z = __builtin_amdgcn_mfma_f32_16x16x32_bf16(b1[nt], qf[qc][1], z, 0, 0, 0);
                sc[nt] = z;
            }
            float e[4][4];
#pragma unroll
            for (int nt = 0; nt < 4; nt++)
#pragma unroll
                for (int r = 0; r < 4; r++) e[nt][r] = exp2f(sc[nt][r]);
            float s0 = (e[0][0] + e[0][1]) + (e[0][2] + e[0][3]);
            float s1 = (e[1][0] + e[1][1]) + (e[1][2] + e[1][3]);
            float s2 = (e[2][0] + e[2][1]) + (e[2][2] + e[2][3]);
            float s3 = (e[3][0] + e[3][1]) + (e[3][2] + e[3][3]);
            if (qc == 0) ls0 += (s0 + s1) + (s2 + s3);
            else         ls1 += (s0 + s1) + (s2 + s3);
            u32 w[8];
            w[0] = pk2(e[0][0], e[0][1]); w[1] = pk2(e[0][2], e[0][3]);
            w[2] = pk2(e[1][0], e[1][1]); w[3] = pk2(e[1][2], e[1][3]);
            w[4] = pk2(e[2][0], e[2][1]); w[5] = pk2(e[2][2], e[2][3]);
            w[6] = pk2(e[3][0], e[3][1]); w[7] = pk2(e[3][2], e[3][3]);
            pa[qc][0] = *(short8*)&w[0];
            pa[qc][1] = *(short8*)&w[4];
        }
#pragma unroll
        for (int d = 0; d < 4; d++) {
            int vswz = ((2 * d + (c16 >> 3)) & 3) << 4;
            short8 vb0 = *(const short8*)&lVT[(d * 16 + c16) * 72 + ((g4 * 8) ^ vswz)];
            short8 vb1 = *(const short8*)&lVT[(d * 16 + c16) * 72 + ((32 + g4 * 8) ^ vswz)];
            o[0][d] = __builtin_amdgcn_mfma_f32_16x16x32_bf16(pa[0][0], vb0, o[0][d], 0, 0, 0);
            o[0][d] = __builtin_amdgcn_mfma_f32_16x16x32_bf16(pa[0][1], vb1, o[0][d], 0, 0, 0);
            o[1][d] = __builtin_amdgcn_mfma_f32_16x16x32_bf16(pa[1][0], vb0, o[1][d], 0, 0, 0);
            o[1][d] = __builtin_amdgcn_mfma_f32_16x16x32_bf16(pa[1][1], vb1, o[1][d], 0, 0, 0);
        }
    }

    ls0 += __shfl_xor(ls0, 16); ls0 += __shfl_xor(ls0, 32);
    ls1 += __shfl_xor(ls1, 16); ls1 += __shfl_xor(ls1, 32);
    size_t slab = (size_t)(sp * 16 + bh) * 2048;
    if (g4 == 0) {
        Lpart[slab + qbase + c16] = ls0;
        Lpart[slab + qbase + 16 + c16] = ls1;
    }
#pragma unroll
    for (int qc = 0; qc < 2; qc++) {
        u16* Ob = Opart + (slab + qbase + qc * 16) * 64;
#pragma unroll
        for (int d = 0; d < 4; d++)
#pragma unroll
            for (int r = 0; r < 4; r++)
                Ob[(size_t)(4 * g4 + r) * 64 + d * 16 + c16] = f2b(o[qc][d][r]);
    }
}

// ---------------- causal attention: 128-row Q tiles paired (p, 15-p), 34 key-tiles ----------
// grid 512: 16 bh x 8 p x 4 sp; sp strides the 34-tile list by 4 -> 8-9 tiles/block, uniform.
__global__ __launch_bounds__(256, 2) void attn_causal_paired(
    const u16* __restrict__ Qp, int q_stride,
    const u16* __restrict__ Kp, int kv_stride,
    const u16* __restrict__ Vp,
    u16* __restrict__ Opart,     // [4][16][2048][64] bf16
    float* __restrict__ Lpart)   // [4][16][2048]
{
    __shared__ u16 lK[64 * 72];
    __shared__ u16 lVT[64 * 72];
    int tid = threadIdx.x, wave = tid >> 6, lane = tid & 63;
    int g4 = lane >> 4, c16 = lane & 15;
    int id = blockIdx.x;
    int bh = (id & 7) | ((id >> 3 & 1) << 3);
    int rest = id >> 4;            // 0..31
    int p = rest & 7;              // pair: 128-row q-tiles p and 15-p
    int sp = rest >> 3;            // 0..3
    int TqA = p, TqB = 15 - p;
    int splitA = 2 * p + 2;        // A-side tile count; total = 34
    size_t rowbase = (size_t)(bh >> 3) * 2048;
    int hoff = (bh & 7) * 64;
    const u16* Q = Qp + rowbase * q_stride + hoff;
    const u16* K = Kp + rowbase * kv_stride + hoff;
    const u16* V = Vp + rowbase * kv_stride + hoff;

    int qbA = TqA * 128 + wave * 32;
    int qbB = TqB * 128 + wave * 32;
    short8 qfA[2][2], qfB[2][2];
#pragma unroll
    for (int qc = 0; qc < 2; qc++) {
        qfA[qc][0] = *(const short8*)&Q[(size_t)(qbA + qc * 16 + c16) * q_stride + g4 * 8];
        qfA[qc][1] = *(const short8*)&Q[(size_t)(qbA + qc * 16 + c16) * q_stride + g4 * 8 + 32];
        qfB[qc][0] = *(const short8*)&Q[(size_t)(qbB + qc * 16 + c16) * q_stride + g4 * 8];
        qfB[qc][1] = *(const short8*)&Q[(size_t)(qbB + qc * 16 + c16) * q_stride + g4 * 8 + 32];
    }

    int kr = tid >> 2, ks = (tid & 3) * 16;
    int krow = 16 * (2 * (kr >> 5) + ((kr >> 2) & 1)) + 4 * ((kr >> 3) & 3) + (kr & 3);
    const u16* Kbase = K + (size_t)kr * kv_stride + ks;
    int vk0 = (tid >> 3) * 2, vs = (tid & 7) * 8;
    const u16* Vbase = V + (size_t)vk0 * kv_stride + vs;

    int4 kv0, kv1, vv0, vv1;
    auto load_tile = [&](int kt) {
        const u16* kp = Kbase + (size_t)kt * 64 * kv_stride;
        kv0 = *(const int4*)(kp);
        kv1 = *(const int4*)(kp + 8);
        const u16* vp = Vbase + (size_t)kt * 64 * kv_stride;
        vv0 = *(const int4*)(vp);
        vv1 = *(const int4*)(vp + kv_stride);
    };
    auto store_tile = [&]() {
        *(int4*)&lK[krow * 72 + ks] = kv0;
        *(int4*)&lK[krow * 72 + ks + 8] = kv1;
        const u16* pa_ = (const u16*)&vv0;
        const u16* pb_ = (const u16*)&vv1;
#pragma unroll
        for (int j = 0; j < 8; j++) {
            int dh = vs + j;
            int keyS = vk0 ^ (((dh >> 3) & 3) << 4);
            u32 w = (u32)pa_[j] | ((u32)pb_[j] << 16);
            *(u32*)&lVT[dh * 72 + keyS] = w;
        }
    };

    floatx4 oA[2][4], oB[2][4];
#pragma unroll
    for (int qc = 0; qc < 2; qc++)
#pragma unroll
        for (int d = 0; d < 4; d++) {
            oA[qc][d] = (floatx4){0.f, 0.f, 0.f, 0.f};
            oB[qc][d] = (floatx4){0.f, 0.f, 0.f, 0.f};
        }
    float lsA0 = 0.f, lsA1 = 0.f, lsB0 = 0.f, lsB1 = 0.f;

    auto compute_tile = [&](short8 (&qf)[2][2], floatx4 (&oacc)[2][4], float& l0, float& l1,
                            int qb, int kt, bool dg) {
        short8 b0[4], b1[4];
#pragma unroll
        for (int nt = 0; nt < 4; nt++) {
            b0[nt] = *(const short8*)&lK[(nt * 16 + c16) * 72 + g4 * 8];
            b1[nt] = *(const short8*)&lK[(nt * 16 + c16) * 72 + g4 * 8 + 32];
        }
        short8 pa[2][2];
#pragma unroll
        for (int qc = 0; qc < 2; qc++) {
            floatx4 sc[4];
#pragma unroll
            for (int nt = 0; nt < 4; nt++) {
                floatx4 z = (floatx4){0.f, 0.f, 0.f, 0.f};
                z = __builtin_amdgcn_mfma_f32_16x16x32_bf16(b0[nt], qf[qc][0], z, 0, 0, 0);
                z = __builtin_amdgcn_mfma_f32_16x16x32_bf16(b1[nt], qf[qc][1], z, 0, 0, 0);
                sc[nt] = z;
            }
            if (dg) {
                int qr = qb + qc * 16 + c16;
#pragma unroll
                for (int nt = 0; nt < 4; nt++) {
                    int key0 = kt * 64 + 8 * g4 + 4 * (nt & 1) + 32 * (nt >> 1);
#pragma unroll
                    for (int r = 0; r < 4; r++)
                        if (key0 + r > qr) sc[nt][r] = -1e30f;
                }
            }
            float e[4][4];
#pragma unroll
            for (int nt = 0; nt < 4; nt++)
#pragma unroll
                for (int r = 0; r < 4; r++) e[nt][r] = exp2f(sc[nt][r]);
            float s0 = (e[0][0] + e[0][1]) + (e[0][2] + e[0][3]);
            float s1 = (e[1][0] + e[1][1]) + (e[1][2] + e[1][3]);
            float s2 = (e[2][0] + e[2][1]) + (e[2][2] + e[2][3]);
            float s3 = (e[3][0] + e[3][1]) + (e[3][2] + e[3][3]);
            if (qc == 0) l0 += (s0 + s1) + (s2 + s3);
            else         l1 += (s0 + s1) + (s2 + s3);
            u32 w[8];
            w[0] = pk2(e[0][0], e[0][1]); w[1] = pk2(e[0][2], e[0][3]);
            w[2] = pk2(e[1][0], e[1][1]); w[3] = pk2(e[1][2], e[1][3]);
            w[4] = pk2(e[2][0], e[2][1]); w[5] = pk2(e[2][2], e[2][3]);
            w[6] = pk2(e[3][0], e[3][1]); w[7] = pk2(e[3][2], e[3][3]);
            pa[qc][0] = *(short8*)&w[0];
            pa[qc][1] = *(short8*)&w[4];
        }
#pragma unroll
        for (int d = 0; d < 4; d++) {
            int vswz = ((2 * d + (c16 >> 3)) & 3) << 4;
            short8 vb0 = *(const short8*)&lVT[(d * 16 + c16) * 72 + ((g4 * 8) ^ vswz)];
            short8 vb1 = *(const short8*)&lVT[(d * 16 + c16) * 72 + ((32 + g4 * 8) ^ vswz)];
            oacc[0][d] = __builtin_amdgcn_mfma_f32_16x16x32_bf16(pa[0][0], vb0, oacc[0][d], 0, 0, 0);
            oacc[0][d] = __builtin_amdgcn_mfma_f32_16x16x32_bf16(pa[0][1], vb1, oacc[0][d], 0, 0, 0);
            oacc[1][d] = __builtin_amdgcn_mfma_f32_16x16x32_bf16(pa[1][0], vb0, oacc[1][d], 0, 0, 0);
            oacc[1][d] = __builtin_amdgcn_mfma_f32_16x16x32_bf16(pa[1][1], vb1, oacc[1][d], 0, 0, 0);
        }
    };

    int t = sp;
    load_tile(t < splitA ? t : t - splitA);
    for (; t < 34; t += 4) {
        __syncthreads();
        store_tile();
        __syncthreads();
        if (t + 4 < 34) { int tn = t + 4; load_tile(tn < splitA ? tn : tn - splitA); }
        if (t < splitA) compute_tile(qfA, oA, lsA0, lsA1, qbA, t, t >= 2 * TqA);
        else {
            int kt = t - splitA;
            compute_tile(qfB, oB, lsB0, lsB1, qbB, kt, kt >= 2 * TqB);
        }
    }

    lsA0 += __shfl_xor(lsA0, 16); lsA0 += __shfl_xor(lsA0, 32);
    lsA1 += __shfl_xor(lsA1, 16); lsA1 += __shfl_xor(lsA1, 32);
    lsB0 += __shfl_xor(lsB0, 16); lsB0 += __shfl_xor(lsB0, 32);
    lsB1 += __shfl_xor(lsB1, 16); lsB1 += __shfl_xor(lsB1, 32);
    size_t slab = (size_t)(sp * 16 + bh) * 2048;
    if (g4 == 0) {
        Lpart[slab + qbA + c16] = lsA0;
        Lpart[slab + qbA + 16 + c16] = lsA1;
        Lpart[slab + qbB + c16] = lsB0;
        Lpart[slab + qbB + 16 + c16] = lsB1;
    }
#pragma unroll
    for (int qc = 0; qc < 2; qc++) {
        u16* ObA = Opart + (slab + qbA + qc * 16) * 64;
        u16* ObB = Opart + (slab + qbB + qc * 16) * 64;
#pragma unroll
        for (int d = 0; d < 4; d++)
#pragma unroll
            for (int r = 0; r < 4; r++) {
                ObA[(size_t)(4 * g4 + r) * 64 + d * 16 + c16] = f2b(oA[qc][d][r]);
                ObB[(size_t)(4 * g4 + r) * 64 + d * 16 + c16] = f2b(oB[qc][d][r]);
            }
    }
}

// ---------------- combine 4 bf16 split partials -> bf16 [4096][512] ----------------
__global__ __launch_bounds__(256) void attn_combine(
    const ushort4* __restrict__ Op,  // [4][16][2048][16 ushort4]
    const float* __restrict__ Lp,    // [4][16][2048]
    ushort4* __restrict__ out)       // [4096][128 ushort4]
{
    int e = blockIdx.x * 256 + threadIdx.x;        // 0 .. 524287
    int dh4 = e & 15;
    int qrow = (e >> 4) & 2047;
    int bh = e >> 15;
    int li = bh * 2048 + qrow;
    float l = (Lp[li] + Lp[32768 + li]) + (Lp[65536 + li] + Lp[98304 + li]);
    float inv = 1.f / l;
    ushort4 a = Op[e];
    ushort4 b = Op[524288 + e];
    ushort4 c = Op[2 * 524288 + e];
    ushort4 d = Op[3 * 524288 + e];
    ushort4 o;
    o.x = f2b(((b2f(a.x) + b2f(b.x)) + (b2f(c.x) + b2f(d.x))) * inv);
    o.y = f2b(((b2f(a.y) + b2f(b.y)) + (b2f(c.y) + b2f(d.y))) * inv);
    o.z = f2b(((b2f(a.z) + b2f(b.z)) + (b2f(c.z) + b2f(d.z))) * inv);
    o.w = f2b(((b2f(a.w) + b2f(b.w)) + (b2f(c.w) + b2f(d.w))) * inv);
    int row = (bh >> 3) * 2048 + qrow;
    out[(size_t)row * 128 + (bh & 7) * 16 + dh4] = o;
}

// ---------------- LayerNorm (row=512), in = bf16 slab0 + slab1, emits fp32 and/or bf16 ------
__global__ __launch_bounds__(256) void ln_kernel(const u16* __restrict__ in0,
                                                 const u16* __restrict__ in1,
                                                 const float* __restrict__ g,
                                                 const float* __restrict__ b,
                                                 float* __restrict__ out_f,
                                                 u16* __restrict__ out_b)
{
    const int D = 512;
    int row = blockIdx.x, tid = threadIdx.x;
    size_t base = (size_t)row * D;
    float v0 = b2f(in0[base + tid]) + b2f(in1[base + tid]);
    float v1 = b2f(in0[base + tid + 256]) + b2f(in1[base + tid + 256]);
    float s = v0 + v1, ss = v0 * v0 + v1 * v1;
#pragma unroll
    for (int off = 1; off < 64; off <<= 1) { s += __shfl_xor(s, off); ss += __shfl_xor(ss, off); }
    __shared__ float red[8];
    int wave = tid >> 6, lane = tid & 63;
    if (lane == 0) { red[wave] = s; red[4 + wave] = ss; }
    __syncthreads();
    float st = red[0] + red[1] + red[2] + red[3];
    float sst = red[4] + red[5] + red[6] + red[7];
    float mu = st * (1.f / 512.f);
    float var = sst * (1.f / 512.f) - mu * mu;
    float rs = rsqrtf(var + 1e-5f);
    float y0 = (v0 - mu) * rs * g[tid] + b[tid];
    float y1 = (v1 - mu) * rs * g[tid + 256] + b[tid + 256];
    if (out_f) { out_f[base + tid] = y0; out_f[base + tid + 256] = y1; }
    if (out_b) { out_b[base + tid] = f2b(y0); out_b[base + tid + 256] = f2b(y1); }
}

// ---------------- launch ----------------
extern "C" void kernel_launch(void* const* d_in, const int* in_sizes, int n_in,
                              void* d_out, int out_size, void* d_ws, size_t ws_size,
                              hipStream_t stream)
{
    (void)in_sizes; (void)n_in; (void)out_size; (void)ws_size;
    const float* x     = (const float*)d_in[0];
    const float* enc   = (const float*)d_in[1];
    const float* m_wq  = (const float*)d_in[2];  const float* m_bq = (const float*)d_in[3];
    const float* m_wk  = (const float*)d_in[4];  const float* m_bk = (const float*)d_in[5];
    const float* m_wv  = (const float*)d_in[6];  const float* m_bv = (const float*)d_in[7];
    const float* m_wo  = (const float*)d_in[8];  const float* m_bo = (const float*)d_in[9];
    const float* c_wq  = (const float*)d_in[10]; const float* c_bq = (const float*)d_in[11];
    const float* c_wk  = (const float*)d_in[12]; const float* c_bk = (const float*)d_in[13];
    const float* c_wv  = (const float*)d_in[14]; const float* c_bv = (const float*)d_in[15];
    const float* c_wo  = (const float*)d_in[16]; const float* c_bo = (const float*)d_in[17];
    const float* ln1_g = (const float*)d_in[18]; const float* ln1_b = (const float*)d_in[19];
    const float* ln2_g = (const float*)d_in[20]; const float* ln2_b = (const float*)d_in[21];
    const float* ln3_g = (const float*)d_in[22]; const float* ln3_b = (const float*)d_in[23];
    const float* ff_w1 = (const float*)d_in[24]; const float* ff_b1 = (const float*)d_in[25];
    const float* ff_w2 = (const float*)d_in[26]; const float* ff_b2 = (const float*)d_in[27];

    char* base = (char*)d_ws; size_t off = 0;
    auto alloc = [&](size_t bytes) -> void* {
        void* p = base + off; off = (off + bytes + 255) & ~(size_t)255; return p;
    };
    u16*   Wqkv_m = (u16*)alloc(1536 * 512 * 2);
    u16*   Wo_m   = (u16*)alloc(512 * 512 * 2);
    u16*   Wq_c   = (u16*)alloc(512 * 512 * 2);
    u16*   Wkv_c  = (u16*)alloc(1024 * 512 * 2);
    u16*   Wo_c   = (u16*)alloc(512 * 512 * 2);
    u16*   W1t    = (u16*)alloc(2048 * 512 * 2);
    u16*   W2t    = (u16*)alloc(512 * 2048 * 2);
    float* bqkv_m = (float*)alloc(1536 * 4);
    float* bkv_c  = (float*)alloc(1024 * 4);
    u16*   xb     = (u16*)alloc((size_t)4096 * 512 * 2);
    u16*   encb   = (u16*)alloc((size_t)4096 * 512 * 2);
    u16*   qkvm   = (u16*)alloc((size_t)4096 * 1536 * 2);
    u16*   attnm  = (u16*)alloc((size_t)4096 * 512 * 2);
    u16*   y01    = (u16*)alloc((size_t)2 * 4096 * 512 * 2);   // K-split bf16 partials
    u16*   x1b    = (u16*)alloc((size_t)4096 * 512 * 2);
    u16*   qc     = (u16*)alloc((size_t)4096 * 512 * 2);
    u16*   kvc    = (u16*)alloc((size_t)4096 * 1024 * 2);
    u16*   attnc  = (u16*)alloc((size_t)4096 * 512 * 2);
    u16*   x2b    = (u16*)alloc((size_t)4096 * 512 * 2);
    u16*   h      = (u16*)alloc((size_t)4096 * 2048 * 2);
    u16*   Opart  = (u16*)alloc((size_t)4 * 16 * 2048 * 64 * 2);
    float* Lpart  = (float*)alloc((size_t)4 * 16 * 2048 * 4);

    // ---- preprocessing: 3 launches ----
    TP16 tp;
    tp.e[0] = {m_wq, Wqkv_m,              512, 512};
    tp.e[1] = {m_wk, Wqkv_m + 512 * 512,  512, 512};
    tp.e[2] = {m_wv, Wqkv_m + 1024 * 512, 512, 512};
    tp.e[3] = {m_wo, Wo_m,                512, 512};
    tp.e[4] = {c_wq, Wq_c,                512, 512};
    tp.e[5] = {c_wk, Wkv_c,               512, 512};
    tp.e[6] = {c_wv, Wkv_c + 512 * 512,   512, 512};
    tp.e[7] = {c_wo, Wo_c,                512, 512};
    for (int k = 0; k < 4; k++)
        tp.e[8 + k]  = {ff_w1 + 512 * k,        W1t + k * 512 * 512, 2048, 512};
    for (int k = 0; k < 4; k++)
        tp.e[12 + k] = {ff_w2 + (size_t)512 * k * 512, W2t + 512 * k, 512, 2048};
    transpose_convert16<<<dim3(16, 16, 16), dim3(32, 8), 0, stream>>>(tp);
    gather_bias<<<10, 256, 0, stream>>>(m_bq, m_bk, m_bv, c_bk, c_bv, bqkv_m, bkv_c);
    cvt_bf16_2<<<2048, 256, 0, stream>>>((const float4*)x, (ushort4*)xb,
                                         (const float4*)enc, (ushort4*)encb);

    // ---- fused QKV_m + KV_c projections (KV_c has no upstream deps) ----
    gemm128_dual<<<dim3(32, 20), 256, 0, stream>>>(
        xb, Wqkv_m, bqkv_m, qkvm, 1536, 512,
        encb, Wkv_c, bkv_c, kvc, 1024,
        12, 512, 512, 512);

    // ---- self attention block ----
    attn_causal_paired<<<512, 256, 0, stream>>>(qkvm, 1536, qkvm + 512, 1536, qkvm + 1024,
                                                Opart, Lpart);
    attn_combine<<<2048, 256, 0, stream>>>((const ushort4*)Opart, Lpart, (ushort4*)attnm);
    gemm64x128s<<<dim3(64, 4, 2), 256, 0, stream>>>(attnm, 512, Wo_m, 512, 256,
                                                    m_bo, x, nullptr, y01, 512);
    ln_kernel<<<4096, 256, 0, stream>>>(y01, y01 + (size_t)4096 * 512, ln1_g, ln1_b,
                                        nullptr, x1b);

    // ---- cross attention block ----
    gemm64x128<<<dim3(64, 4), 256, 0, stream>>>(x1b, 512, Wq_c, 512, 512,
                                                c_bq, nullptr, nullptr, qc, 512, 512, 0);
    attn_cross<<<1024, 256, 0, stream>>>(qc, 512, kvc, 1024, kvc + 512,
                                         Opart, Lpart);
    attn_combine<<<2048, 256, 0, stream>>>((const ushort4*)Opart, Lpart, (ushort4*)attnc);
    gemm64x128s<<<dim3(64, 4, 2), 256, 0, stream>>>(attnc, 512, Wo_c, 512, 256,
                                                    c_bo, nullptr, x1b, y01, 512);
    ln_kernel<<<4096, 256, 0, stream>>>(y01, y01 + (size_t)4096 * 512, ln2_g, ln2_b,
                                        nullptr, x2b);

    // ---- feed forward ----
    gemm128<<<dim3(32, 16), 256, 0, stream>>>(x2b, 512, W1t, 512, 512,
                                              ff_b1, h, 2048, 0, 1);
    gemm64x128s<<<dim3(64, 4, 2), 256, 0, stream>>>(h, 2048, W2t, 2048, 1024,
                                                    ff_b2, nullptr, x2b, y01, 512);
    ln_kernel<<<4096, 256, 0, stream>>>(y01, y01 + (size_t)4096 * 512, ln3_g, ln3_b,
                                        (float*)d_out, nullptr);
}

// Round 6
// 291.528 us; speedup vs baseline: 1.1198x; 1.1198x over previous
//
#include <hip/hip_runtime.h>
#include <hip/hip_bf16.h>

typedef __attribute__((ext_vector_type(8))) short short8;
typedef __attribute__((ext_vector_type(4))) float floatx4;
typedef unsigned short u16;
typedef unsigned int u32;

#define QSCALE 0.1803368801111244f   // 0.125 * log2(e): folded into Q so softmax is exp2(S)

__device__ __forceinline__ u16 f2b(float f) {
    union { float f; u32 u; } v; v.f = f;
    u32 r = v.u + 0x7fffu + ((v.u >> 16) & 1u);   // RNE
    return (u16)(r >> 16);
}

__device__ __forceinline__ float b2f(u16 b) {
    u32 u = ((u32)b) << 16;
    union { u32 u; float f; } v; v.u = u;
    return v.f;
}

__device__ __forceinline__ u32 pk2(float a, float b) {
    __hip_bfloat162 w = __float22bfloat162_rn(make_float2(a, b));
    return *(u32*)&w;
}

// fast GELU: tanh form via hw exp2+rcp. |err| vs erf-GELU <= ~1e-3 for |x|<6,
// below bf16 quantization of h. gelu = x*t/(t+1), t = exp2(2log2e*(c1*x + c3*x^3)).
__device__ __forceinline__ float gelu_fast(float v) {
    float u = v * (0.7978845608028654f + 0.03567740814183367f * v * v);
    float t = exp2f(fminf(2.8853900817779268f * u, 80.f));
    return v * t * __builtin_amdgcn_rcpf(t + 1.f);
}

__device__ __forceinline__ void gload(const u16* g, u16* l) {
    __builtin_amdgcn_global_load_lds((const __attribute__((address_space(1))) void*)g,
                                     (__attribute__((address_space(3))) void*)l, 16, 0, 0);
}

// ---------------- batched weight transpose + fp32->bf16 (16 x 512x512 tiles) ----------------
struct TPent { const float* s; u16* d; int O; int dI; };
struct TP16 { TPent e[16]; };
__global__ __launch_bounds__(256) void transpose_convert16(TP16 p) {
    __shared__ float t[32][33];
    TPent e = p.e[blockIdx.z];
    int o0 = blockIdx.x * 32, i0 = blockIdx.y * 32;
    int tx = threadIdx.x, ty = threadIdx.y;
#pragma unroll
    for (int k = 0; k < 32; k += 8) t[ty + k][tx] = e.s[(size_t)(i0 + ty + k) * e.O + o0 + tx];
    __syncthreads();
#pragma unroll
    for (int k = 0; k < 32; k += 8) e.d[(size_t)(o0 + ty + k) * e.dI + i0 + tx] = f2b(t[tx][ty + k]);
}

// gather 5 bias vectors into 2 concat buffers. grid 10 x 256
__global__ __launch_bounds__(256) void gather_bias(const float* b0, const float* b1, const float* b2,
                                                   const float* b3, const float* b4,
                                                   float* dqkv, float* dkv) {
    int i = blockIdx.x * 256 + threadIdx.x;
    if      (i < 512)  dqkv[i] = b0[i];
    else if (i < 1024) dqkv[i] = b1[i - 512];
    else if (i < 1536) dqkv[i] = b2[i - 1024];
    else if (i < 2048) dkv[i - 1536] = b3[i - 1536];
    else               dkv[i - 1536] = b4[i - 2048];
}

// fp32 -> bf16 for x and enc in one launch. grid 2048 x 256, 4 elems each.
__global__ __launch_bounds__(256) void cvt_bf16_2(const float4* __restrict__ s0, ushort4* __restrict__ d0,
                                                  const float4* __restrict__ s1, ushort4* __restrict__ d1) {
    int i = blockIdx.x * 256 + threadIdx.x;
    float4 v = s0[i];
    ushort4 o; o.x = f2b(v.x); o.y = f2b(v.y); o.z = f2b(v.z); o.w = f2b(v.w);
    d0[i] = o;
    v = s1[i];
    o.x = f2b(v.x); o.y = f2b(v.y); o.z = f2b(v.z); o.w = f2b(v.w);
    d1[i] = o;
}

// ---------------- GEMM 64x128, BK=64: C = A[M,K] @ Bt[N,K] + epilogue. grid (M/64, N/128) ----
// LDS rows are 64 u16 (128 B): XOR-swizzled via pre-swizzled global source column
// (skseg ^= (row&7)<<3) + matching read-side XOR, keeping ds_read_b128 conflict-free.
__global__ __launch_bounds__(256) void gemm64x128(
    const u16* __restrict__ A, int lda,
    const u16* __restrict__ B, int ldb,
    int K,
    const float* __restrict__ bias,
    const float* __restrict__ residual,
    float* __restrict__ out_f, u16* __restrict__ out_b,
    int out_stride, int scale_ncols, int gelu_flag)
{
    __shared__ u16 lA[64 * 64];
    __shared__ u16 lB[128 * 64];
    int tid = threadIdx.x, wave = tid >> 6, lane = tid & 63;
    int g4 = lane >> 4, c16 = lane & 15;
    int swz = (c16 & 7) << 3;
    int bm = blockIdx.x * 64, bn = blockIdx.y * 128;
    int wm = (wave >> 1) * 32, wn = (wave & 1) * 64;
    int srow = tid >> 3, skseg = ((tid & 7) * 8) ^ ((srow & 7) << 3);
    const u16* Ar = A + (size_t)(bm + srow) * lda + skseg;
    const u16* Br = B + (size_t)(bn + srow) * ldb + skseg;
    size_t a32 = (size_t)32 * lda, b32 = (size_t)32 * ldb;

    floatx4 acc[2][4];
#pragma unroll
    for (int i = 0; i < 2; i++)
#pragma unroll
        for (int j = 0; j < 4; j++) acc[i][j] = (floatx4){0.f, 0.f, 0.f, 0.f};

    for (int kt = 0; kt < K; kt += 64) {
        __syncthreads();
        gload(Ar + kt,           lA + wave * 512);
        gload(Ar + kt + a32,     lA + 2048 + wave * 512);
        gload(Br + kt,           lB + wave * 512);
        gload(Br + kt + b32,     lB + 2048 + wave * 512);
        gload(Br + kt + 2 * b32, lB + 4096 + wave * 512);
        gload(Br + kt + 3 * b32, lB + 6144 + wave * 512);
        __syncthreads();
        short8 aF[2][2], bF[2][4];
#pragma unroll
        for (int kk = 0; kk < 2; kk++) {
            int ko = (g4 * 8 + kk * 32) ^ swz;
#pragma unroll
            for (int i = 0; i < 2; i++) aF[kk][i] = *(const short8*)&lA[(wm + i * 16 + c16) * 64 + ko];
#pragma unroll
            for (int j = 0; j < 4; j++) bF[kk][j] = *(const short8*)&lB[(wn + j * 16 + c16) * 64 + ko];
        }
#pragma unroll
        for (int kk = 0; kk < 2; kk++)
#pragma unroll
            for (int i = 0; i < 2; i++)
#pragma unroll
                for (int j = 0; j < 4; j++)
                    acc[i][j] = __builtin_amdgcn_mfma_f32_16x16x32_bf16(aF[kk][i], bF[kk][j], acc[i][j], 0, 0, 0);
    }

#pragma unroll
    for (int i = 0; i < 2; i++) {
        int row0 = bm + wm + i * 16 + g4 * 4;
#pragma unroll
        for (int j = 0; j < 4; j++) {
            int col = bn + wn + j * 16 + c16;
            float bv = bias[col];
#pragma unroll
            for (int r = 0; r < 4; r++) {
                int row = row0 + r;
                float v = acc[i][j][r] + bv;
                if (col < scale_ncols) v *= QSCALE;
                if (gelu_flag) v = gelu_fast(v);
                if (residual) v += residual[(size_t)row * out_stride + col];
                if (out_f) out_f[(size_t)row * out_stride + col] = v;
                else       out_b[(size_t)row * out_stride + col] = f2b(v);
            }
        }
    }
}

// ---------------- dual GEMM 64x128, BK=64 (QKV_m for by<ys, KV_c for by>=ys), bf16 out ------
__global__ __launch_bounds__(256) void gemm64x128_dual(
    const u16* __restrict__ A0, const u16* __restrict__ B0, const float* __restrict__ bias0,
    u16* __restrict__ out0, int ostride0, int scale0,
    const u16* __restrict__ A1, const u16* __restrict__ B1, const float* __restrict__ bias1,
    u16* __restrict__ out1, int ostride1,
    int ys, int K, int lda, int ldb)
{
    __shared__ u16 lA[64 * 64];
    __shared__ u16 lB[128 * 64];
    int tid = threadIdx.x, wave = tid >> 6, lane = tid & 63;
    int g4 = lane >> 4, c16 = lane & 15;
    int swz = (c16 & 7) << 3;
    int by = blockIdx.y;
    const u16* A; const u16* B; const float* bias; u16* out; int ostride, scaleN, bn;
    if (by < ys) { A = A0; B = B0; bias = bias0; out = out0; ostride = ostride0; scaleN = scale0; bn = by * 128; }
    else         { A = A1; B = B1; bias = bias1; out = out1; ostride = ostride1; scaleN = 0;      bn = (by - ys) * 128; }
    int bm = blockIdx.x * 64;
    int wm = (wave >> 1) * 32, wn = (wave & 1) * 64;
    int srow = tid >> 3, skseg = ((tid & 7) * 8) ^ ((srow & 7) << 3);
    const u16* Ar = A + (size_t)(bm + srow) * lda + skseg;
    const u16* Br = B + (size_t)(bn + srow) * ldb + skseg;
    size_t a32 = (size_t)32 * lda, b32 = (size_t)32 * ldb;

    floatx4 acc[2][4];
#pragma unroll
    for (int i = 0; i < 2; i++)
#pragma unroll
        for (int j = 0; j < 4; j++) acc[i][j] = (floatx4){0.f, 0.f, 0.f, 0.f};

    for (int kt = 0; kt < K; kt += 64) {
        __syncthreads();
        gload(Ar + kt,           lA + wave * 512);
        gload(Ar + kt + a32,     lA + 2048 + wave * 512);
        gload(Br + kt,           lB + wave * 512);
        gload(Br + kt + b32,     lB + 2048 + wave * 512);
        gload(Br + kt + 2 * b32, lB + 4096 + wave * 512);
        gload(Br + kt + 3 * b32, lB + 6144 + wave * 512);
        __syncthreads();
        short8 aF[2][2], bF[2][4];
#pragma unroll
        for (int kk = 0; kk < 2; kk++) {
            int ko = (g4 * 8 + kk * 32) ^ swz;
#pragma unroll
            for (int i = 0; i < 2; i++) aF[kk][i] = *(const short8*)&lA[(wm + i * 16 + c16) * 64 + ko];
#pragma unroll
            for (int j = 0; j < 4; j++) bF[kk][j] = *(const short8*)&lB[(wn + j * 16 + c16) * 64 + ko];
        }
#pragma unroll
        for (int kk = 0; kk < 2; kk++)
#pragma unroll
            for (int i = 0; i < 2; i++)
#pragma unroll
                for (int j = 0; j < 4; j++)
                    acc[i][j] = __builtin_amdgcn_mfma_f32_16x16x32_bf16(aF[kk][i], bF[kk][j], acc[i][j], 0, 0, 0);
    }

#pragma unroll
    for (int i = 0; i < 2; i++) {
        int row0 = bm + wm + i * 16 + g4 * 4;
#pragma unroll
        for (int j = 0; j < 4; j++) {
            int col = bn + wn + j * 16 + c16;
            float bv = bias[col];
#pragma unroll
            for (int r = 0; r < 4; r++) {
                float v = acc[i][j][r] + bv;
                if (col < scaleN) v *= QSCALE;
                out[(size_t)(row0 + r) * ostride + col] = f2b(v);
            }
        }
    }
}

// ---------------- GEMM 64x64, BK=64, bf16 out, single-pass (used for Q_c) ----------------
__global__ __launch_bounds__(256) void gemm64x64(
    const u16* __restrict__ A, int lda,
    const u16* __restrict__ B, int ldb,
    int K,
    const float* __restrict__ bias,
    u16* __restrict__ out_b,
    int out_stride, int scale_ncols)
{
    __shared__ u16 lA[64 * 64];
    __shared__ u16 lB[64 * 64];
    int tid = threadIdx.x, wave = tid >> 6, lane = tid & 63;
    int g4 = lane >> 4, c16 = lane & 15;
    int swz = (c16 & 7) << 3;
    int bm = blockIdx.x * 64, bn = blockIdx.y * 64;
    int wm = wave * 16;
    int srow = tid >> 3, skseg = ((tid & 7) * 8) ^ ((srow & 7) << 3);
    const u16* Ar = A + (size_t)(bm + srow) * lda + skseg;
    const u16* Br = B + (size_t)(bn + srow) * ldb + skseg;
    size_t a32 = (size_t)32 * lda, b32 = (size_t)32 * ldb;

    floatx4 acc[4];
#pragma unroll
    for (int j = 0; j < 4; j++) acc[j] = (floatx4){0.f, 0.f, 0.f, 0.f};

    for (int kt = 0; kt < K; kt += 64) {
        __syncthreads();
        gload(Ar + kt,       lA + wave * 512);
        gload(Ar + kt + a32, lA + 2048 + wave * 512);
        gload(Br + kt,       lB + wave * 512);
        gload(Br + kt + b32, lB + 2048 + wave * 512);
        __syncthreads();
        short8 aF[2], bF[2][4];
#pragma unroll
        for (int kk = 0; kk < 2; kk++) {
            int ko = (g4 * 8 + kk * 32) ^ swz;
            aF[kk] = *(const short8*)&lA[(wm + c16) * 64 + ko];
#pragma unroll
            for (int j = 0; j < 4; j++) bF[kk][j] = *(const short8*)&lB[(j * 16 + c16) * 64 + ko];
        }
#pragma unroll
        for (int kk = 0; kk < 2; kk++)
#pragma unroll
            for (int j = 0; j < 4; j++)
                acc[j] = __builtin_amdgcn_mfma_f32_16x16x32_bf16(aF[kk], bF[kk][j], acc[j], 0, 0, 0);
    }

    int row0 = bm + wm + g4 * 4;
#pragma unroll
    for (int j = 0; j < 4; j++) {
        int col = bn + j * 16 + c16;
        float bv = bias[col];
#pragma unroll
        for (int r = 0; r < 4; r++) {
            int row = row0 + r;
            float v = acc[j][r] + bv;
            if (col < scale_ncols) v *= QSCALE;
            out_b[(size_t)row * out_stride + col] = f2b(v);
        }
    }
}

// ---------------- GEMM 64x64 K-split-2, BK=64: bf16 partials. grid (M/64, N/64, 2) ----------
// sp==0 adds bias + residual (fp32 OR bf16 source). Consumer (LN) adds the two bf16 slabs.
__global__ __launch_bounds__(256) void gemm64x64s(
    const u16* __restrict__ A, int lda,
    const u16* __restrict__ B, int ldb,
    int Ksub,
    const float* __restrict__ bias,
    const float* __restrict__ res_f,
    const u16* __restrict__ res_b,
    u16* __restrict__ out0, int out_stride)
{
    __shared__ u16 lA[64 * 64];
    __shared__ u16 lB[64 * 64];
    int tid = threadIdx.x, wave = tid >> 6, lane = tid & 63;
    int g4 = lane >> 4, c16 = lane & 15;
    int swz = (c16 & 7) << 3;
    int bm = blockIdx.x * 64, bn = blockIdx.y * 64, sp = blockIdx.z;
    int wm = wave * 16;
    int srow = tid >> 3;
    int skseg = (((tid & 7) * 8) ^ ((srow & 7) << 3)) + sp * Ksub;
    const u16* Ar = A + (size_t)(bm + srow) * lda + skseg;
    const u16* Br = B + (size_t)(bn + srow) * ldb + skseg;
    size_t a32 = (size_t)32 * lda, b32 = (size_t)32 * ldb;

    floatx4 acc[4];
#pragma unroll
    for (int j = 0; j < 4; j++) acc[j] = (floatx4){0.f, 0.f, 0.f, 0.f};

    for (int kt = 0; kt < Ksub; kt += 64) {
        __syncthreads();
        gload(Ar + kt,       lA + wave * 512);
        gload(Ar + kt + a32, lA + 2048 + wave * 512);
        gload(Br + kt,       lB + wave * 512);
        gload(Br + kt + b32, lB + 2048 + wave * 512);
        __syncthreads();
        short8 aF[2], bF[2][4];
#pragma unroll
        for (int kk = 0; kk < 2; kk++) {
            int ko = (g4 * 8 + kk * 32) ^ swz;
            aF[kk] = *(const short8*)&lA[(wm + c16) * 64 + ko];
#pragma unroll
            for (int j = 0; j < 4; j++) bF[kk][j] = *(const short8*)&lB[(j * 16 + c16) * 64 + ko];
        }
#pragma unroll
        for (int kk = 0; kk < 2; kk++)
#pragma unroll
            for (int j = 0; j < 4; j++)
                acc[j] = __builtin_amdgcn_mfma_f32_16x16x32_bf16(aF[kk], bF[kk][j], acc[j], 0, 0, 0);
    }

    u16* out = out0 + (size_t)sp * 4096 * 512;
    int row0 = bm + wm + g4 * 4;
#pragma unroll
    for (int j = 0; j < 4; j++) {
        int col = bn + j * 16 + c16;
        float bv = (sp == 0) ? bias[col] : 0.f;
#pragma unroll
        for (int r = 0; r < 4; r++) {
            int row = row0 + r;
            float v = acc[j][r] + bv;
            if (sp == 0) {
                if (res_f)      v += res_f[(size_t)row * out_stride + col];
                else if (res_b) v += b2f(res_b[(size_t)row * out_stride + col]);
            }
            out[(size_t)row * out_stride + col] = f2b(v);
        }
    }
}

// ============ attention common: 32 q-rows per wave (2 q-subtiles), K/V frags read once ======
// K rows staged in permuted order row(k) = 16*(2*(k>>5)+((k>>2)&1)) + 4*((k>>3)&3) + (k&3):
// S^T lands so PV A-frags are a pure register repack. V transposed+swizzled in LDS.

// ---------------- cross attention: 128-row Q blocks, 4-way key split. grid 1024 -------------
__global__ __launch_bounds__(256, 3) void attn_cross(
    const u16* __restrict__ Qp, int q_stride,
    const u16* __restrict__ Kp, int kv_stride,
    const u16* __restrict__ Vp,
    u16* __restrict__ Opart,     // [4][16][2048][64] bf16
    float* __restrict__ Lpart)   // [4][16][2048]
{
    __shared__ u16 lK[64 * 72];
    __shared__ u16 lVT[64 * 72];
    int tid = threadIdx.x, wave = tid >> 6, lane = tid & 63;
    int g4 = lane >> 4, c16 = lane & 15;
    int id = blockIdx.x;
    int bh = (id & 7) | ((id >> 3 & 1) << 3);
    int rest = id >> 4;            // 0..63
    int qt = rest & 15;            // 128-row q tile
    int sp = rest >> 4;            // 0..3
    size_t rowbase = (size_t)(bh >> 3) * 2048;
    int hoff = (bh & 7) * 64;
    const u16* Q = Qp + rowbase * q_stride + hoff;
    const u16* K = Kp + rowbase * kv_stride + hoff;
    const u16* V = Vp + rowbase * kv_stride + hoff;

    int qbase = qt * 128 + wave * 32;
    short8 qf[2][2];
#pragma unroll
    for (int qc = 0; qc < 2; qc++) {
        qf[qc][0] = *(const short8*)&Q[(size_t)(qbase + qc * 16 + c16) * q_stride + g4 * 8];
        qf[qc][1] = *(const short8*)&Q[(size_t)(qbase + qc * 16 + c16) * q_stride + g4 * 8 + 32];
    }

    int kr = tid >> 2, ks = (tid & 3) * 16;
    int krow = 16 * (2 * (kr >> 5) + ((kr >> 2) & 1)) + 4 * ((kr >> 3) & 3) + (kr & 3);
    const u16* Kbase = K + (size_t)kr * kv_stride + ks;
    int vk0 = (tid >> 3) * 2, vs = (tid & 7) * 8;
    const u16* Vbase = V + (size_t)vk0 * kv_stride + vs;

    int4 kv0, kv1, vv0, vv1;
    auto load_tile = [&](int kt) {
        const u16* kp = Kbase + (size_t)kt * 64 * kv_stride;
        kv0 = *(const int4*)(kp);
        kv1 = *(const int4*)(kp + 8);
        const u16* vp = Vbase + (size_t)kt * 64 * kv_stride;
        vv0 = *(const int4*)(vp);
        vv1 = *(const int4*)(vp + kv_stride);
    };
    auto store_tile = [&]() {
        *(int4*)&lK[krow * 72 + ks] = kv0;
        *(int4*)&lK[krow * 72 + ks + 8] = kv1;
        const u16* pa = (const u16*)&vv0;
        const u16* pb = (const u16*)&vv1;
#pragma unroll
        for (int j = 0; j < 8; j++) {
            int dh = vs + j;
            int keyS = vk0 ^ (((dh >> 3) & 3) << 4);
            u32 w = (u32)pa[j] | ((u32)pb[j] << 16);
            *(u32*)&lVT[dh * 72 + keyS] = w;
        }
    };

    floatx4 o[2][4];
#pragma unroll
    for (int qc = 0; qc < 2; qc++)
#pragma unroll
        for (int d = 0; d < 4; d++) o[qc][d] = (floatx4){0.f, 0.f, 0.f, 0.f};
    float ls0 = 0.f, ls1 = 0.f;

    int kt = sp;
    load_tile(kt);
    for (; kt < 32; kt += 4) {
        __syncthreads();
        store_tile();
        __syncthreads();
        if (kt + 4 < 32) load_tile(kt + 4);

        short8 b0[4], b1[4];
#pragma unroll
        for (int nt = 0; nt < 4; nt++) {
            b0[nt] = *(const short8*)&lK[(nt * 16 + c16) * 72 + g4 * 8];
            b1[nt] = *(const short8*)&lK[(nt * 16 + c16) * 72 + g4 * 8 + 32];
        }
        short8 pa[2][2];
#pragma unroll
        for (int qc = 0; qc < 2; qc++) {
            floatx4 sc[4];
#pragma unroll
            for (int nt = 0; nt < 4; nt++) {
                floatx4 z = (floatx4){0.f, 0.f, 0.f, 0.f};
                z = __builtin_amdgcn_mfma_f32_16x16x32_bf16(b0[nt], qf[qc][0], z, 0, 0, 0);
                z = __builtin_amdgcn_mfma_f32_16x16x32_bf16(b1[nt], qf[qc][1], z, 0, 0, 0);
                sc[nt] = z;
            }
            float e[4][4];
#pragma unroll
            for (int nt = 0; nt < 4; nt++)
#pragma unroll
                for (int r = 0; r < 4; r++) e[nt][r] = exp2f(sc[nt][r]);
            float s0 = (e[0][0] + e[0][1]) + (e[0][2] + e[0][3]);
            float s1 = (e[1][0] + e[1][1]) + (e[1][2] + e[1][3]);
            float s2 = (e[2][0] + e[2][1]) + (e[2][2] + e[2][3]);
            float s3 = (e[3][0] + e[3][1]) + (e[3][2] + e[3][3]);
            if (qc == 0) ls0 += (s0 + s1) + (s2 + s3);
            else         ls1 += (s0 + s1) + (s2 + s3);
            u32 w[8];
            w[0] = pk2(e[0][0], e[0][1]); w[1] = pk2(e[0][2], e[0][3]);
            w[2] = pk2(e[1][0], e[1][1]); w[3] = pk2(e[1][2], e[1][3]);
            w[4] = pk2(e[2][0], e[2][1]); w[5] = pk2(e[2][2], e[2][3]);
            w[6] = pk2(e[3][0], e[3][1]); w[7] = pk2(e[3][2], e[3][3]);
            pa[qc][0] = *(short8*)&w[0];
            pa[qc][1] = *(short8*)&w[4];
        }
#pragma unroll
        for (int d = 0; d < 4; d++) {
            int vswz = ((2 * d + (c16 >> 3)) & 3) << 4;
            short8 vb0 = *(const short8*)&lVT[(d * 16 + c16) * 72 + ((g4 * 8) ^ vswz)];
            short8 vb1 = *(const short8*)&lVT[(d * 16 + c16) * 72 + ((32 + g4 * 8) ^ vswz)];
            o[0][d] = __builtin_amdgcn_mfma_f32_16x16x32_bf16(pa[0][0], vb0, o[0][d], 0, 0, 0);
            o[0][d] = __builtin_amdgcn_mfma_f32_16x16x32_bf16(pa[0][1], vb1, o[0][d], 0, 0, 0);
            o[1][d] = __builtin_amdgcn_mfma_f32_16x16x32_bf16(pa[1][0], vb0, o[1][d], 0, 0, 0);
            o[1][d] = __builtin_amdgcn_mfma_f32_16x16x32_bf16(pa[1][1], vb1, o[1][d], 0, 0, 0);
        }
    }

    ls0 += __shfl_xor(ls0, 16); ls0 += __shfl_xor(ls0, 32);
    ls1 += __shfl_xor(ls1, 16); ls1 += __shfl_xor(ls1, 32);
    size_t slab = (size_t)(sp * 16 + bh) * 2048;
    if (g4 == 0) {
        Lpart[slab + qbase + c16] = ls0;
        Lpart[slab + qbase + 16 + c16] = ls1;
    }
#pragma unroll
    for (int qc = 0; qc < 2; qc++) {
        u16* Ob = Opart + (slab + qbase + qc * 16) * 64;
#pragma unroll
        for (int d = 0; d < 4; d++)
#pragma unroll
            for (int r = 0; r < 4; r++)
                Ob[(size_t)(4 * g4 + r) * 64 + d * 16 + c16] = f2b(o[qc][d][r]);
    }
}

// ---------------- causal attention: 128-row Q tiles paired (p, 15-p), 34 key-tiles ----------
// grid 512: 16 bh x 8 p x 4 sp; sp strides the 34-tile list by 4 -> 8-9 tiles/block, uniform.
__global__ __launch_bounds__(256, 2) void attn_causal_paired(
    const u16* __restrict__ Qp, int q_stride,
    const u16* __restrict__ Kp, int kv_stride,
    const u16* __restrict__ Vp,
    u16* __restrict__ Opart,     // [4][16][2048][64] bf16
    float* __restrict__ Lpart)   // [4][16][2048]
{
    __shared__ u16 lK[64 * 72];
    __shared__ u16 lVT[64 * 72];
    int tid = threadIdx.x, wave = tid >> 6, lane = tid & 63;
    int g4 = lane >> 4, c16 = lane & 15;
    int id = blockIdx.x;
    int bh = (id & 7) | ((id >> 3 & 1) << 3);
    int rest = id >> 4;            // 0..31
    int p = rest & 7;              // pair: 128-row q-tiles p and 15-p
    int sp = rest >> 3;            // 0..3
    int TqA = p, TqB = 15 - p;
    int splitA = 2 * p + 2;        // A-side tile count; total = 34
    size_t rowbase = (size_t)(bh >> 3) * 2048;
    int hoff = (bh & 7) * 64;
    const u16* Q = Qp + rowbase * q_stride + hoff;
    const u16* K = Kp + rowbase * kv_stride + hoff;
    const u16* V = Vp + rowbase * kv_stride + hoff;

    int qbA = TqA * 128 + wave * 32;
    int qbB = TqB * 128 + wave * 32;
    short8 qfA[2][2], qfB[2][2];
#pragma unroll
    for (int qc = 0; qc < 2; qc++) {
        qfA[qc][0] = *(const short8*)&Q[(size_t)(qbA + qc * 16 + c16) * q_stride + g4 * 8];
        qfA[qc][1] = *(const short8*)&Q[(size_t)(qbA + qc * 16 + c16) * q_stride + g4 * 8 + 32];
        qfB[qc][0] = *(const short8*)&Q[(size_t)(qbB + qc * 16 + c16) * q_stride + g4 * 8];
        qfB[qc][1] = *(const short8*)&Q[(size_t)(qbB + qc * 16 + c16) * q_stride + g4 * 8 + 32];
    }

    int kr = tid >> 2, ks = (tid & 3) * 16;
    int krow = 16 * (2 * (kr >> 5) + ((kr >> 2) & 1)) + 4 * ((kr >> 3) & 3) + (kr & 3);
    const u16* Kbase = K + (size_t)kr * kv_stride + ks;
    int vk0 = (tid >> 3) * 2, vs = (tid & 7) * 8;
    const u16* Vbase = V + (size_t)vk0 * kv_stride + vs;

    int4 kv0, kv1, vv0, vv1;
    auto load_tile = [&](int kt) {
        const u16* kp = Kbase + (size_t)kt * 64 * kv_stride;
        kv0 = *(const int4*)(kp);
        kv1 = *(const int4*)(kp + 8);
        const u16* vp = Vbase + (size_t)kt * 64 * kv_stride;
        vv0 = *(const int4*)(vp);
        vv1 = *(const int4*)(vp + kv_stride);
    };
    auto store_tile = [&]() {
        *(int4*)&lK[krow * 72 + ks] = kv0;
        *(int4*)&lK[krow * 72 + ks + 8] = kv1;
        const u16* pa_ = (const u16*)&vv0;
        const u16* pb_ = (const u16*)&vv1;
#pragma unroll
        for (int j = 0; j < 8; j++) {
            int dh = vs + j;
            int keyS = vk0 ^ (((dh >> 3) & 3) << 4);
            u32 w = (u32)pa_[j] | ((u32)pb_[j] << 16);
            *(u32*)&lVT[dh * 72 + keyS] = w;
        }
    };

    floatx4 oA[2][4], oB[2][4];
#pragma unroll
    for (int qc = 0; qc < 2; qc++)
#pragma unroll
        for (int d = 0; d < 4; d++) {
            oA[qc][d] = (floatx4){0.f, 0.f, 0.f, 0.f};
            oB[qc][d] = (floatx4){0.f, 0.f, 0.f, 0.f};
        }
    float lsA0 = 0.f, lsA1 = 0.f, lsB0 = 0.f, lsB1 = 0.f;

    auto compute_tile = [&](short8 (&qf)[2][2], floatx4 (&oacc)[2][4], float& l0, float& l1,
                            int qb, int kt, bool dg) {
        short8 b0[4], b1[4];
#pragma unroll
        for (int nt = 0; nt < 4; nt++) {
            b0[nt] = *(const short8*)&lK[(nt * 16 + c16) * 72 + g4 * 8];
            b1[nt] = *(const short8*)&lK[(nt * 16 + c16) * 72 + g4 * 8 + 32];
        }
        short8 pa[2][2];
#pragma unroll
        for (int qc = 0; qc < 2; qc++) {
            floatx4 sc[4];
#pragma unroll
            for (int nt = 0; nt < 4; nt++) {
                floatx4 z = (floatx4){0.f, 0.f, 0.f, 0.f};
                z = __builtin_amdgcn_mfma_f32_16x16x32_bf16(b0[nt], qf[qc][0], z, 0, 0, 0);
                z = __builtin_amdgcn_mfma_f32_16x16x32_bf16(b1[nt], qf[qc][1], z, 0, 0, 0);
                sc[nt] = z;
            }
            if (dg) {
                int qr = qb + qc * 16 + c16;
#pragma unroll
                for (int nt = 0; nt < 4; nt++) {
                    int key0 = kt * 64 + 8 * g4 + 4 * (nt & 1) + 32 * (nt >> 1);
#pragma unroll
                    for (int r = 0; r < 4; r++)
                        if (key0 + r > qr) sc[nt][r] = -1e30f;
                }
            }
            float e[4][4];
#pragma unroll
            for (int nt = 0; nt < 4; nt++)
#pragma unroll
                for (int r = 0; r < 4; r++) e[nt][r] = exp2f(sc[nt][r]);
            float s0 = (e[0][0] + e[0][1]) + (e[0][2] + e[0][3]);
            float s1 = (e[1][0] + e[1][1]) + (e[1][2] + e[1][3]);
            float s2 = (e[2][0] + e[2][1]) + (e[2][2] + e[2][3]);
            float s3 = (e[3][0] + e[3][1]) + (e[3][2] + e[3][3]);
            if (qc == 0) l0 += (s0 + s1) + (s2 + s3);
            else         l1 += (s0 + s1) + (s2 + s3);
            u32 w[8];
            w[0] = pk2(e[0][0], e[0][1]); w[1] = pk2(e[0][2], e[0][3]);
            w[2] = pk2(e[1][0], e[1][1]); w[3] = pk2(e[1][2], e[1][3]);
            w[4] = pk2(e[2][0], e[2][1]); w[5] = pk2(e[2][2], e[2][3]);
            w[6] = pk2(e[3][0], e[3][1]); w[7] = pk2(e[3][2], e[3][3]);
            pa[qc][0] = *(short8*)&w[0];
            pa[qc][1] = *(short8*)&w[4];
        }
#pragma unroll
        for (int d = 0; d < 4; d++) {
            int vswz = ((2 * d + (c16 >> 3)) & 3) << 4;
            short8 vb0 = *(const short8*)&lVT[(d * 16 + c16) * 72 + ((g4 * 8) ^ vswz)];
            short8 vb1 = *(const short8*)&lVT[(d * 16 + c16) * 72 + ((32 + g4 * 8) ^ vswz)];
            oacc[0][d] = __builtin_amdgcn_mfma_f32_16x16x32_bf16(pa[0][0], vb0, oacc[0][d], 0, 0, 0);
            oacc[0][d] = __builtin_amdgcn_mfma_f32_16x16x32_bf16(pa[0][1], vb1, oacc[0][d], 0, 0, 0);
            oacc[1][d] = __builtin_amdgcn_mfma_f32_16x16x32_bf16(pa[1][0], vb0, oacc[1][d], 0, 0, 0);
            oacc[1][d] = __builtin_amdgcn_mfma_f32_16x16x32_bf16(pa[1][1], vb1, oacc[1][d], 0, 0, 0);
        }
    };

    int t = sp;
    load_tile(t < splitA ? t : t - splitA);
    for (; t < 34; t += 4) {
        __syncthreads();
        store_tile();
        __syncthreads();
        if (t + 4 < 34) { int tn = t + 4; load_tile(tn < splitA ? tn : tn - splitA); }
        if (t < splitA) compute_tile(qfA, oA, lsA0, lsA1, qbA, t, t >= 2 * TqA);
        else {
            int kt = t - splitA;
            compute_tile(qfB, oB, lsB0, lsB1, qbB, kt, kt >= 2 * TqB);
        }
    }

    lsA0 += __shfl_xor(lsA0, 16); lsA0 += __shfl_xor(lsA0, 32);
    lsA1 += __shfl_xor(lsA1, 16); lsA1 += __shfl_xor(lsA1, 32);
    lsB0 += __shfl_xor(lsB0, 16); lsB0 += __shfl_xor(lsB0, 32);
    lsB1 += __shfl_xor(lsB1, 16); lsB1 += __shfl_xor(lsB1, 32);
    size_t slab = (size_t)(sp * 16 + bh) * 2048;
    if (g4 == 0) {
        Lpart[slab + qbA + c16] = lsA0;
        Lpart[slab + qbA + 16 + c16] = lsA1;
        Lpart[slab + qbB + c16] = lsB0;
        Lpart[slab + qbB + 16 + c16] = lsB1;
    }
#pragma unroll
    for (int qc = 0; qc < 2; qc++) {
        u16* ObA = Opart + (slab + qbA + qc * 16) * 64;
        u16* ObB = Opart + (slab + qbB + qc * 16) * 64;
#pragma unroll
        for (int d = 0; d < 4; d++)
#pragma unroll
            for (int r = 0; r < 4; r++) {
                ObA[(size_t)(4 * g4 + r) * 64 + d * 16 + c16] = f2b(oA[qc][d][r]);
                ObB[(size_t)(4 * g4 + r) * 64 + d * 16 + c16] = f2b(oB[qc][d][r]);
            }
    }
}

// ---------------- combine 4 bf16 split partials -> bf16 [4096][512] ----------------
__global__ __launch_bounds__(256) void attn_combine(
    const ushort4* __restrict__ Op,  // [4][16][2048][16 ushort4]
    const float* __restrict__ Lp,    // [4][16][2048]
    ushort4* __restrict__ out)       // [4096][128 ushort4]
{
    int e = blockIdx.x * 256 + threadIdx.x;        // 0 .. 524287
    int dh4 = e & 15;
    int qrow = (e >> 4) & 2047;
    int bh = e >> 15;
    int li = bh * 2048 + qrow;
    float l = (Lp[li] + Lp[32768 + li]) + (Lp[65536 + li] + Lp[98304 + li]);
    float inv = 1.f / l;
    ushort4 a = Op[e];
    ushort4 b = Op[524288 + e];
    ushort4 c = Op[2 * 524288 + e];
    ushort4 d = Op[3 * 524288 + e];
    ushort4 o;
    o.x = f2b(((b2f(a.x) + b2f(b.x)) + (b2f(c.x) + b2f(d.x))) * inv);
    o.y = f2b(((b2f(a.y) + b2f(b.y)) + (b2f(c.y) + b2f(d.y))) * inv);
    o.z = f2b(((b2f(a.z) + b2f(b.z)) + (b2f(c.z) + b2f(d.z))) * inv);
    o.w = f2b(((b2f(a.w) + b2f(b.w)) + (b2f(c.w) + b2f(d.w))) * inv);
    int row = (bh >> 3) * 2048 + qrow;
    out[(size_t)row * 128 + (bh & 7) * 16 + dh4] = o;
}

// ---------------- LayerNorm (row=512), in = bf16 slab0 + slab1, emits fp32 and/or bf16 ------
__global__ __launch_bounds__(256) void ln_kernel(const u16* __restrict__ in0,
                                                 const u16* __restrict__ in1,
                                                 const float* __restrict__ g,
                                                 const float* __restrict__ b,
                                                 float* __restrict__ out_f,
                                                 u16* __restrict__ out_b)
{
    const int D = 512;
    int row = blockIdx.x, tid = threadIdx.x;
    size_t base = (size_t)row * D;
    float v0 = b2f(in0[base + tid]) + b2f(in1[base + tid]);
    float v1 = b2f(in0[base + tid + 256]) + b2f(in1[base + tid + 256]);
    float s = v0 + v1, ss = v0 * v0 + v1 * v1;
#pragma unroll
    for (int off = 1; off < 64; off <<= 1) { s += __shfl_xor(s, off); ss += __shfl_xor(ss, off); }
    __shared__ float red[8];
    int wave = tid >> 6, lane = tid & 63;
    if (lane == 0) { red[wave] = s; red[4 + wave] = ss; }
    __syncthreads();
    float st = red[0] + red[1] + red[2] + red[3];
    float sst = red[4] + red[5] + red[6] + red[7];
    float mu = st * (1.f / 512.f);
    float var = sst * (1.f / 512.f) - mu * mu;
    float rs = rsqrtf(var + 1e-5f);
    float y0 = (v0 - mu) * rs * g[tid] + b[tid];
    float y1 = (v1 - mu) * rs * g[tid + 256] + b[tid + 256];
    if (out_f) { out_f[base + tid] = y0; out_f[base + tid + 256] = y1; }
    if (out_b) { out_b[base + tid] = f2b(y0); out_b[base + tid + 256] = f2b(y1); }
}

// ---------------- launch ----------------
extern "C" void kernel_launch(void* const* d_in, const int* in_sizes, int n_in,
                              void* d_out, int out_size, void* d_ws, size_t ws_size,
                              hipStream_t stream)
{
    (void)in_sizes; (void)n_in; (void)out_size; (void)ws_size;
    const float* x     = (const float*)d_in[0];
    const float* enc   = (const float*)d_in[1];
    const float* m_wq  = (const float*)d_in[2];  const float* m_bq = (const float*)d_in[3];
    const float* m_wk  = (const float*)d_in[4];  const float* m_bk = (const float*)d_in[5];
    const float* m_wv  = (const float*)d_in[6];  const float* m_bv = (const float*)d_in[7];
    const float* m_wo  = (const float*)d_in[8];  const float* m_bo = (const float*)d_in[9];
    const float* c_wq  = (const float*)d_in[10]; const float* c_bq = (const float*)d_in[11];
    const float* c_wk  = (const float*)d_in[12]; const float* c_bk = (const float*)d_in[13];
    const float* c_wv  = (const float*)d_in[14]; const float* c_bv = (const float*)d_in[15];
    const float* c_wo  = (const float*)d_in[16]; const float* c_bo = (const float*)d_in[17];
    const float* ln1_g = (const float*)d_in[18]; const float* ln1_b = (const float*)d_in[19];
    const float* ln2_g = (const float*)d_in[20]; const float* ln2_b = (const float*)d_in[21];
    const float* ln3_g = (const float*)d_in[22]; const float* ln3_b = (const float*)d_in[23];
    const float* ff_w1 = (const float*)d_in[24]; const float* ff_b1 = (const float*)d_in[25];
    const float* ff_w2 = (const float*)d_in[26]; const float* ff_b2 = (const float*)d_in[27];

    char* base = (char*)d_ws; size_t off = 0;
    auto alloc = [&](size_t bytes) -> void* {
        void* p = base + off; off = (off + bytes + 255) & ~(size_t)255; return p;
    };
    u16*   Wqkv_m = (u16*)alloc(1536 * 512 * 2);
    u16*   Wo_m   = (u16*)alloc(512 * 512 * 2);
    u16*   Wq_c   = (u16*)alloc(512 * 512 * 2);
    u16*   Wkv_c  = (u16*)alloc(1024 * 512 * 2);
    u16*   Wo_c   = (u16*)alloc(512 * 512 * 2);
    u16*   W1t    = (u16*)alloc(2048 * 512 * 2);
    u16*   W2t    = (u16*)alloc(512 * 2048 * 2);
    float* bqkv_m = (float*)alloc(1536 * 4);
    float* bkv_c  = (float*)alloc(1024 * 4);
    u16*   xb     = (u16*)alloc((size_t)4096 * 512 * 2);
    u16*   encb   = (u16*)alloc((size_t)4096 * 512 * 2);
    u16*   qkvm   = (u16*)alloc((size_t)4096 * 1536 * 2);
    u16*   attnm  = (u16*)alloc((size_t)4096 * 512 * 2);
    u16*   y01    = (u16*)alloc((size_t)2 * 4096 * 512 * 2);   // K-split bf16 partials
    u16*   x1b    = (u16*)alloc((size_t)4096 * 512 * 2);
    u16*   qc     = (u16*)alloc((size_t)4096 * 512 * 2);
    u16*   kvc    = (u16*)alloc((size_t)4096 * 1024 * 2);
    u16*   attnc  = (u16*)alloc((size_t)4096 * 512 * 2);
    u16*   x2b    = (u16*)alloc((size_t)4096 * 512 * 2);
    u16*   h      = (u16*)alloc((size_t)4096 * 2048 * 2);
    u16*   Opart  = (u16*)alloc((size_t)4 * 16 * 2048 * 64 * 2);
    float* Lpart  = (float*)alloc((size_t)4 * 16 * 2048 * 4);

    // ---- preprocessing: 3 launches ----
    TP16 tp;
    tp.e[0] = {m_wq, Wqkv_m,              512, 512};
    tp.e[1] = {m_wk, Wqkv_m + 512 * 512,  512, 512};
    tp.e[2] = {m_wv, Wqkv_m + 1024 * 512, 512, 512};
    tp.e[3] = {m_wo, Wo_m,                512, 512};
    tp.e[4] = {c_wq, Wq_c,                512, 512};
    tp.e[5] = {c_wk, Wkv_c,               512, 512};
    tp.e[6] = {c_wv, Wkv_c + 512 * 512,   512, 512};
    tp.e[7] = {c_wo, Wo_c,                512, 512};
    for (int k = 0; k < 4; k++)
        tp.e[8 + k]  = {ff_w1 + 512 * k,        W1t + k * 512 * 512, 2048, 512};
    for (int k = 0; k < 4; k++)
        tp.e[12 + k] = {ff_w2 + (size_t)512 * k * 512, W2t + 512 * k, 512, 2048};
    transpose_convert16<<<dim3(16, 16, 16), dim3(32, 8), 0, stream>>>(tp);
    gather_bias<<<10, 256, 0, stream>>>(m_bq, m_bk, m_bv, c_bk, c_bv, bqkv_m, bkv_c);
    cvt_bf16_2<<<2048, 256, 0, stream>>>((const float4*)x, (ushort4*)xb,
                                         (const float4*)enc, (ushort4*)encb);

    // ---- fused QKV_m + KV_c projections (KV_c has no upstream deps) ----
    gemm64x128_dual<<<dim3(64, 20), 256, 0, stream>>>(
        xb, Wqkv_m, bqkv_m, qkvm, 1536, 512,
        encb, Wkv_c, bkv_c, kvc, 1024,
        12, 512, 512, 512);

    // ---- self attention block ----
    attn_causal_paired<<<512, 256, 0, stream>>>(qkvm, 1536, qkvm + 512, 1536, qkvm + 1024,
                                                Opart, Lpart);
    attn_combine<<<2048, 256, 0, stream>>>((const ushort4*)Opart, Lpart, (ushort4*)attnm);
    gemm64x64s<<<dim3(64, 8, 2), 256, 0, stream>>>(attnm, 512, Wo_m, 512, 256,
                                                   m_bo, x, nullptr, y01, 512);
    ln_kernel<<<4096, 256, 0, stream>>>(y01, y01 + (size_t)4096 * 512, ln1_g, ln1_b,
                                        nullptr, x1b);

    // ---- cross attention block ----
    gemm64x64<<<dim3(64, 8), 256, 0, stream>>>(x1b, 512, Wq_c, 512, 512,
                                               c_bq, qc, 512, 512);
    attn_cross<<<1024, 256, 0, stream>>>(qc, 512, kvc, 1024, kvc + 512,
                                         Opart, Lpart);
    attn_combine<<<2048, 256, 0, stream>>>((const ushort4*)Opart, Lpart, (ushort4*)attnc);
    gemm64x64s<<<dim3(64, 8, 2), 256, 0, stream>>>(attnc, 512, Wo_c, 512, 256,
                                                   c_bo, nullptr, x1b, y01, 512);
    ln_kernel<<<4096, 256, 0, stream>>>(y01, y01 + (size_t)4096 * 512, ln2_g, ln2_b,
                                        nullptr, x2b);

    // ---- feed forward ----
    gemm64x128<<<dim3(64, 16), 256, 0, stream>>>(x2b, 512, W1t, 512, 512,
                                                 ff_b1, nullptr, nullptr, h, 2048, 0, 1);
    gemm64x64s<<<dim3(64, 8, 2), 256, 0, stream>>>(h, 2048, W2t, 2048, 1024,
                                                   ff_b2, nullptr, x2b, y01, 512);
    ln_kernel<<<4096, 256, 0, stream>>>(y01, y01 + (size_t)4096 * 512, ln3_g, ln3_b,
                                        (float*)d_out, nullptr);
}